// Round 6
// baseline (261.417 us; speedup 1.0000x reference)
//
#include <hip/hip_runtime.h>
#include <hip/hip_bf16.h>
#include <cstdint>

// GAT 3-layer pipeline, MI355X. B=4, N=2048, Fin=128, nhid=64, H=8, emb=64, nclass=16.
// fp32 tensors; d_out = [image_feature (4*2048*64) | pre (4*16)] fp32.
// Round 6: fp16 packed P-gen + f16 MFMA in attention (halves P-gen VALU, better mantissa
// than bf16), depth-4 register pipeline, K-split x4 layer-2 GEMM (2 -> 8 waves/CU) with
// fp32 partials + epilogue kernel.

#define NN 2048

typedef float f32x4 __attribute__((ext_vector_type(4)));
typedef __bf16 bf16x8 __attribute__((ext_vector_type(8)));
typedef _Float16 f16;
typedef _Float16 f16x8 __attribute__((ext_vector_type(8)));

__device__ __forceinline__ unsigned pkbf(float a, float b) {
  __hip_bfloat162 t = __float22bfloat162_rn(make_float2(a, b));
  unsigned r;
  __builtin_memcpy(&r, &t, 4);
  return r;
}

// ---------------- adj -> u16 mask plane (0xFFFF / 0) ----------------
__global__ __launch_bounds__(256) void build_plane_k(const int* __restrict__ adj,
                                                     unsigned short* __restrict__ plane) {
  const int i = blockIdx.x;
#pragma unroll
  for (int jt = 0; jt < NN / 256; ++jt) {
    const int j = jt * 256 + threadIdx.x;
    plane[(long)i * NN + j] = adj[(long)i * NN + j] > 0 ? 0xFFFFu : 0u;
  }
}

// ---------------- W (fp32 [K x 64] per instance) -> bf16 hi/lo B-frag planes --------
// frag pos for (k,n): ((k>>5)*4 + (n>>4))*512 + (((k>>3)&3)*16 + (n&15))*8 + (k&7)
__global__ __launch_bounds__(256) void swizw_k(const float* __restrict__ W,
                                               __bf16* __restrict__ hi,
                                               __bf16* __restrict__ lo, int K) {
  const long inst = blockIdx.y;
  const float* w = W + inst * K * 64;
  __bf16* h = hi + inst * K * 64;
  __bf16* l = lo + inst * K * 64;
  for (int idx = blockIdx.x * 256 + threadIdx.x; idx < K * 64; idx += gridDim.x * 256) {
    const int k = idx >> 6, n = idx & 63;
    const float v = w[idx];
    const __bf16 vh = (__bf16)v;
    const __bf16 vl = (__bf16)(v - (float)vh);
    const int pos = ((k >> 5) * 4 + (n >> 4)) * 512 + (((k >> 3) & 3) * 16 + (n & 15)) * 8 + (k & 7);
    h[pos] = vh;
    l[pos] = vl;
  }
}

// ---------------- MFMA GEMM (M rows, N=64). 128 thr, 32 rows/block. ----------------
// KS==1 (gridDim.z==1): fused epilogue -> E/G fp32, F/H fp16, WhB fp16 frags.
// KS>1: k-slice [ks*K/KS, ...), fp32 partial C to pC, no epilogue.
struct GemmLd {
  float4 a0, a1;
  bf16x8 bh[4], bl[4];
};

__global__ __launch_bounds__(128) void gemm_mfma_k(
    const float* __restrict__ Aall, const __bf16* __restrict__ WFhi,
    const __bf16* __restrict__ WFlo, const float* __restrict__ avecAll,
    f16* __restrict__ WhBAll, float* __restrict__ Eo, float* __restrict__ Go,
    f16* __restrict__ Fo, f16* __restrict__ Ho, float* __restrict__ pC,
    int K, int KS, long aStrideB) {
  const int p = blockIdx.y;
  const int ks = blockIdx.z;
  const float* A = Aall + (long)(p & 3) * aStrideB;
  const long wfOff = (long)(p >> 2) * K * 64;
  const bf16x8* BhF = (const bf16x8*)(WFhi + wfOff);
  const bf16x8* BlF = (const bf16x8*)(WFlo + wfOff);

  const int t = threadIdx.x, lane = t & 63, wave = t >> 6;
  const int quad = lane >> 4, lm = lane & 15;
  const int i0w = blockIdx.x * 32 + wave * 16;
  const float* Arow = A + (long)(i0w + lm) * K;
  const int kBeg = ks * (K / KS), kEnd = kBeg + K / KS;

  f32x4 acc[4];
#pragma unroll
  for (int nt = 0; nt < 4; ++nt) acc[nt] = (f32x4){0.f, 0.f, 0.f, 0.f};

  auto LOAD = [&](GemmLd& L, int k0) {
    L.a0 = *(const float4*)(Arow + k0 + quad * 8);
    L.a1 = *(const float4*)(Arow + k0 + quad * 8 + 4);
    const int bbase = (k0 >> 5) * 256 + lane;
#pragma unroll
    for (int nt = 0; nt < 4; ++nt) {
      L.bh[nt] = BhF[bbase + nt * 64];
      L.bl[nt] = BlF[bbase + nt * 64];
    }
  };
  auto STEP = [&](const GemmLd& L) {
    const float av8[8] = {L.a0.x, L.a0.y, L.a0.z, L.a0.w, L.a1.x, L.a1.y, L.a1.z, L.a1.w};
    bf16x8 ah, al;
#pragma unroll
    for (int j = 0; j < 8; ++j) {
      const __bf16 h = (__bf16)av8[j];
      ah[j] = h;
      al[j] = (__bf16)(av8[j] - (float)h);
    }
#pragma unroll
    for (int nt = 0; nt < 4; ++nt) {
      acc[nt] = __builtin_amdgcn_mfma_f32_16x16x32_bf16(ah, L.bh[nt], acc[nt], 0, 0, 0);
      acc[nt] = __builtin_amdgcn_mfma_f32_16x16x32_bf16(al, L.bh[nt], acc[nt], 0, 0, 0);
      acc[nt] = __builtin_amdgcn_mfma_f32_16x16x32_bf16(ah, L.bl[nt], acc[nt], 0, 0, 0);
    }
  };

  GemmLd La, Lb;
  LOAD(La, kBeg);
  for (int k0 = kBeg; k0 < kEnd; k0 += 64) {
    LOAD(Lb, k0 + 32);
    STEP(La);
    LOAD(La, (k0 + 64 < kEnd) ? k0 + 64 : kBeg);
    STEP(Lb);
  }

  if (KS > 1) {
    // partial fp32 C: [(p*KS + ks)*NN + row]*64 + col
    float* pc = pC + ((long)(p * KS + ks) * NN) * 64;
#pragma unroll
    for (int reg = 0; reg < 4; ++reg) {
      const int row = i0w + quad * 4 + reg;
#pragma unroll
      for (int nt = 0; nt < 4; ++nt) pc[(long)row * 64 + nt * 16 + lm] = acc[nt][reg];
    }
    return;
  }

  const float* av = avecAll + (long)(p >> 2) * 128;
  f16* WhB = WhBAll + (long)p * NN * 64;
  float* E = Eo + (long)p * NN;
  float* G = Go + (long)p * NN;
  f16* F = Fo + (long)p * NN;
  f16* Hh = Ho + (long)p * NN;

  // fused esrc/edst: per-row dot with a_lo / a_hi, butterfly over the 16 lm lanes
  float alo[4], ahi[4];
#pragma unroll
  for (int nt = 0; nt < 4; ++nt) {
    alo[nt] = av[nt * 16 + lm];
    ahi[nt] = av[64 + nt * 16 + lm];
  }
#pragma unroll
  for (int reg = 0; reg < 4; ++reg) {
    float es = 0.f, ed = 0.f;
#pragma unroll
    for (int nt = 0; nt < 4; ++nt) {
      es += acc[nt][reg] * alo[nt];
      ed += acc[nt][reg] * ahi[nt];
    }
#pragma unroll
    for (int m = 1; m < 16; m <<= 1) {
      es += __shfl_xor(es, m);
      ed += __shfl_xor(ed, m);
    }
    if (lm == 0) {
      const int r = i0w + quad * 4 + reg;
      E[r] = __expf(es);
      G[r] = __expf(0.2f * es);
      F[r] = (f16)__expf(ed);
      Hh[r] = (f16)__expf(0.2f * ed);
    }
  }

  // WhB fp16 frag stores (rows here are attention-k)
  const int r0 = i0w + quad * 4;
  const long base = ((long)(r0 >> 5) * 4) * 512 + (((r0 >> 3) & 3) * 16 + lm) * 8 + (r0 & 7);
#pragma unroll
  for (int nt = 0; nt < 4; ++nt) {
    union { f16 h[4]; uint2 u; } pk;
#pragma unroll
    for (int q = 0; q < 4; ++q) pk.h[q] = (f16)acc[nt][q];
    *(uint2*)(WhB + base + nt * 512) = pk.u;
  }
}

// ---------------- layer-2 GEMM epilogue: sum KS partials -> E/G/F/H + WhB frags ----
__global__ __launch_bounds__(256) void gemm_epi_k(
    const float* __restrict__ pC, const float* __restrict__ avec,
    f16* __restrict__ WhBAll, float* __restrict__ Eo, float* __restrict__ Go,
    f16* __restrict__ Fo, f16* __restrict__ Ho, int KS) {
  const int inst = blockIdx.y;
  const int t = threadIdx.x;
  const int row = blockIdx.x * 16 + (t >> 4);
  const int cg = t & 15;
  f32x4 c = (f32x4){0.f, 0.f, 0.f, 0.f};
  for (int ks = 0; ks < KS; ++ks)
    c += *(const f32x4*)(pC + (((long)(inst * KS + ks) * NN) + row) * 64 + cg * 4);
  float es = 0.f, ed = 0.f;
#pragma unroll
  for (int q = 0; q < 4; ++q) {
    const int n = cg * 4 + q;
    es += c[q] * avec[n];
    ed += c[q] * avec[64 + n];
  }
#pragma unroll
  for (int m = 1; m < 16; m <<= 1) {
    es += __shfl_xor(es, m);
    ed += __shfl_xor(ed, m);
  }
  if (cg == 0) {
    Eo[(long)inst * NN + row] = __expf(es);
    Go[(long)inst * NN + row] = __expf(0.2f * es);
    Fo[(long)inst * NN + row] = (f16)__expf(ed);
    Ho[(long)inst * NN + row] = (f16)__expf(0.2f * ed);
  }
  f16* WhB = WhBAll + (long)inst * NN * 64;
#pragma unroll
  for (int q = 0; q < 4; ++q) {
    const int n = cg * 4 + q;
    const int pos = ((row >> 5) * 4 + (n >> 4)) * 512 + (((row >> 3) & 3) * 16 + (n & 15)) * 8 + (row & 7);
    WhB[pos] = (f16)c[q];
  }
}

// ---------------- attention: P = mask & max(E*F, G*H) in fp16, f16 MFMA ----------------
// 4 waves/block, 32 rows/wave, depth-4 register pipeline, no LDS/barriers.
struct AttnLd {
  f16x8 F, H;
  uint4 m0, m1;
  f16x8 b[4];
};

__global__ __launch_bounds__(256) void attn_k(
    const f16* __restrict__ WhBAll, const float* __restrict__ Eb,
    const float* __restrict__ Gb, const f16* __restrict__ Fb,
    const f16* __restrict__ Hb, const unsigned short* __restrict__ plane,
    float* __restrict__ out1, int rowStride, long strideB,
    int jsCount, float* __restrict__ partAcc, float* __restrict__ partSum) {
  const int p = blockIdx.z;
  const int js = blockIdx.y;
  const f16x8* bp = (const f16x8*)(WhBAll + (long)p * NN * 64);
  const float* E = Eb + (long)p * NN;
  const float* G = Gb + (long)p * NN;
  const f16* F = Fb + (long)p * NN;
  const f16* Hv = Hb + (long)p * NN;
  const int t = threadIdx.x, lane = t & 63, wave = t >> 6;
  const int quad = lane >> 4, lm = lane & 15;
  const int i0 = blockIdx.x * 128 + wave * 32;
  const int kbBeg = js * (64 / jsCount);
  const int kbEnd = kbBeg + 64 / jsCount;

  const f16 e0 = (f16)E[i0 + lm], g0 = (f16)G[i0 + lm];
  const f16 e1 = (f16)E[i0 + 16 + lm], g1 = (f16)G[i0 + 16 + lm];
  f16x8 e0v, g0v, e1v, g1v;
#pragma unroll
  for (int j = 0; j < 8; ++j) { e0v[j] = e0; g0v[j] = g0; e1v[j] = e1; g1v[j] = g1; }
  const unsigned short* mp0 = plane + (long)(i0 + lm) * NN;
  const unsigned short* mp1 = plane + (long)(i0 + 16 + lm) * NN;

  f16x8 ones;
#pragma unroll
  for (int j = 0; j < 8; ++j) ones[j] = (lm == 0) ? (f16)1.0f : (f16)0.0f;

  f32x4 acc0[4], acc1[4], sum0, sum1;
#pragma unroll
  for (int nt = 0; nt < 4; ++nt) {
    acc0[nt] = (f32x4){0.f, 0.f, 0.f, 0.f};
    acc1[nt] = (f32x4){0.f, 0.f, 0.f, 0.f};
  }
  sum0 = (f32x4){0.f, 0.f, 0.f, 0.f};
  sum1 = (f32x4){0.f, 0.f, 0.f, 0.f};

  auto LOAD = [&](AttnLd& L, int kb) {
    const int c0 = kb * 32 + quad * 8;
    L.F = *(const f16x8*)(F + c0);
    L.H = *(const f16x8*)(Hv + c0);
    L.m0 = *(const uint4*)(mp0 + c0);
    L.m1 = *(const uint4*)(mp1 + c0);
#pragma unroll
    for (int nt = 0; nt < 4; ++nt) L.b[nt] = bp[(kb * 4 + nt) * 64 + lane];
  };
  auto STEP = [&](const AttnLd& L) {
    union { f16x8 v; uint4 u; } A0, A1;
    A0.v = __builtin_elementwise_max(e0v * L.F, g0v * L.H);
    A1.v = __builtin_elementwise_max(e1v * L.F, g1v * L.H);
    A0.u.x &= L.m0.x; A0.u.y &= L.m0.y; A0.u.z &= L.m0.z; A0.u.w &= L.m0.w;
    A1.u.x &= L.m1.x; A1.u.y &= L.m1.y; A1.u.z &= L.m1.z; A1.u.w &= L.m1.w;
#pragma unroll
    for (int nt = 0; nt < 4; ++nt) {
      acc0[nt] = __builtin_amdgcn_mfma_f32_16x16x32_f16(A0.v, L.b[nt], acc0[nt], 0, 0, 0);
      acc1[nt] = __builtin_amdgcn_mfma_f32_16x16x32_f16(A1.v, L.b[nt], acc1[nt], 0, 0, 0);
    }
    sum0 = __builtin_amdgcn_mfma_f32_16x16x32_f16(A0.v, ones, sum0, 0, 0, 0);
    sum1 = __builtin_amdgcn_mfma_f32_16x16x32_f16(A1.v, ones, sum1, 0, 0, 0);
  };
  auto w = [&](int kb) { return kb < kbEnd ? kb : kbBeg; };

  AttnLd L0, L1, L2, L3;
  LOAD(L0, kbBeg); LOAD(L1, w(kbBeg + 1)); LOAD(L2, w(kbBeg + 2));
  for (int kb = kbBeg; kb < kbEnd; kb += 4) {
    LOAD(L3, w(kb + 3)); STEP(L0);
    LOAD(L0, w(kb + 4)); STEP(L1);
    LOAD(L1, w(kb + 5)); STEP(L2);
    LOAD(L2, w(kb + 6)); STEP(L3);
  }

  if (jsCount == 1) {
#pragma unroll
    for (int g = 0; g < 2; ++g) {
      const f32x4* acc = g ? acc1 : acc0;
      const f32x4 sm = g ? sum1 : sum0;
#pragma unroll
      for (int reg = 0; reg < 4; ++reg) {
        const int row = i0 + g * 16 + quad * 4 + reg;
        const float ls = __shfl(sm[reg], quad * 16);
        const float il = ls > 0.f ? 1.f / ls : 0.f;
#pragma unroll
        for (int nt = 0; nt < 4; ++nt) {
          float v = acc[nt][reg] * il;
          v = v > 0.f ? v : expm1f(v);  // elu
          out1[(long)(p & 3) * strideB + (long)row * rowStride + (p >> 2) * 64 + nt * 16 + lm] = v;
        }
      }
    }
  } else {
    float* pAcc = partAcc + ((long)p * jsCount + js) * NN * 64;
    float* pSum = partSum + ((long)p * jsCount + js) * NN;
#pragma unroll
    for (int g = 0; g < 2; ++g) {
      const f32x4* acc = g ? acc1 : acc0;
      const f32x4 sm = g ? sum1 : sum0;
#pragma unroll
      for (int reg = 0; reg < 4; ++reg) {
        const int row = i0 + g * 16 + quad * 4 + reg;
#pragma unroll
        for (int nt = 0; nt < 4; ++nt) pAcc[(long)row * 64 + nt * 16 + lm] = acc[nt][reg];
        if (lm == 0) pSum[row] = sm[reg];
      }
    }
  }
}

// ---------------- combine j-split partials: normalize + elu + dual write ----------------
__global__ __launch_bounds__(256) void combine_k(const float* __restrict__ partAcc,
                                                 const float* __restrict__ partSum,
                                                 float* __restrict__ img,
                                                 float* __restrict__ out, int JS) {
  const long idx = (long)blockIdx.x * 256 + threadIdx.x;
  const int cg = idx & 15;
  const int row = (int)((idx >> 4) & (NN - 1));
  const int inst = (int)(idx >> 15);
  f32x4 v = (f32x4){0.f, 0.f, 0.f, 0.f};
  float s = 0.f;
  for (int js = 0; js < JS; ++js) {
    const long b = ((long)inst * JS + js) * NN;
    v += *(const f32x4*)(partAcc + (b + row) * 64 + cg * 4);
    s += partSum[b + row];
  }
  const float il = s > 0.f ? 1.f / s : 0.f;
  f32x4 r;
#pragma unroll
  for (int q = 0; q < 4; ++q) {
    float x = v[q] * il;
    r[q] = x > 0.f ? x : expm1f(x);
  }
  const long o = ((long)inst * NN + row) * 64 + cg * 4;
  *(f32x4*)(img + o) = r;
  *(f32x4*)(out + o) = r;
}

// ---------------- layer-3 Wh3 = imgfeat @ W2 (K=64, Nc=16), fp32 ----------------
__global__ __launch_bounds__(256) void gemm16_k(const float* __restrict__ Aall,
                                                const float* __restrict__ Bw,
                                                float* __restrict__ Call) {
  const int bb = blockIdx.y;
  const float* A = Aall + (long)bb * NN * 64;
  float* C = Call + (long)bb * NN * 16;
  const int r0 = blockIdx.x * 16;
  const int t = threadIdx.x;
  __shared__ float As[16][65];
  __shared__ float Bs[64][16];
  const int c = t & 15, r = t >> 4;
#pragma unroll
  for (int q = 0; q < 4; ++q) {
    const int idx = q * 256 + t;
    As[idx >> 6][idx & 63] = A[(long)(r0 + (idx >> 6)) * 64 + (idx & 63)];
    Bs[idx >> 4][idx & 15] = Bw[idx];
  }
  __syncthreads();
  float acc = 0.f;
#pragma unroll 16
  for (int k = 0; k < 64; ++k) acc += As[r][k] * Bs[k][c];
  C[(long)(r0 + r) * 16 + c] = acc;
}

// ---------------- layer-3 finalize: only attention row 0 matters ----------------
__global__ __launch_bounds__(256) void layer3_k(const float* __restrict__ Wh3,
                                                const float* __restrict__ a2,
                                                const unsigned short* __restrict__ plane,
                                                float* __restrict__ outPre) {
  const int bb = blockIdx.x, t = threadIdx.x;
  const float* W = Wh3 + (long)bb * NN * 16;
  __shared__ float wsum[4];
  __shared__ float vacc[4][16];
  float alo[16], ahi[16];
#pragma unroll
  for (int c = 0; c < 16; ++c) {
    alo[c] = a2[c];
    ahi[c] = a2[16 + c];
  }
  float es = 0.f;
#pragma unroll
  for (int c = 0; c < 16; ++c) es += W[c] * alo[c];

  float lsum = 0.f;
  float acc[16];
#pragma unroll
  for (int c = 0; c < 16; ++c) acc[c] = 0.f;
  for (int j = t; j < NN; j += 256) {
    float ed = 0.f;
#pragma unroll
    for (int c = 0; c < 16; ++c) ed += W[(long)j * 16 + c] * ahi[c];
    float e = es + ed;
    e = fmaxf(e, 0.2f * e);
    const float pv = plane[j] ? __expf(e) : 0.f;
    lsum += pv;
#pragma unroll
    for (int c = 0; c < 16; ++c) acc[c] += pv * W[(long)j * 16 + c];
  }
#pragma unroll
  for (int off = 32; off > 0; off >>= 1) {
    lsum += __shfl_down(lsum, off);
#pragma unroll
    for (int c = 0; c < 16; ++c) acc[c] += __shfl_down(acc[c], off);
  }
  if ((t & 63) == 0) {
    wsum[t >> 6] = lsum;
#pragma unroll
    for (int c = 0; c < 16; ++c) vacc[t >> 6][c] = acc[c];
  }
  __syncthreads();
  if (t < 16) {
    const float a = vacc[0][t] + vacc[1][t] + vacc[2][t] + vacc[3][t];
    const float l = wsum[0] + wsum[1] + wsum[2] + wsum[3];
    float v = a / l;
    v = v > 0.f ? v : expm1f(v);
    outPre[bb * 16 + t] = v;
  }
}

// ---------------- host ----------------
extern "C" void kernel_launch(void* const* d_in, const int* in_sizes, int n_in,
                              void* d_out, int out_size, void* d_ws, size_t ws_size,
                              hipStream_t stream) {
  (void)in_sizes; (void)n_in; (void)out_size; (void)ws_size;
  constexpr int B = 4, N = NN, JS2 = 4, KS2 = 4;

  const float* slices = (const float*)d_in[0];
  const int* adj = (const int*)d_in[1];
  const float* Ws = (const float*)d_in[2];
  const float* As = (const float*)d_in[3];
  const float* W1 = (const float*)d_in[4];
  const float* a1 = (const float*)d_in[5];
  const float* W2 = (const float*)d_in[6];
  const float* a2 = (const float*)d_in[7];
  float* out = (float*)d_out;

  char* w = (char*)d_ws;
  size_t off = 0;
  auto alloc = [&](size_t bytes) {
    void* ptr = w + off;
    off += (bytes + 255) & ~(size_t)255;
    return ptr;
  };
  unsigned short* plane = (unsigned short*)alloc((size_t)N * N * 2);  // 8 MB
  __bf16* WsFh = (__bf16*)alloc((size_t)8 * 128 * 64 * 2);
  __bf16* WsFl = (__bf16*)alloc((size_t)8 * 128 * 64 * 2);
  __bf16* W1Fh = (__bf16*)alloc((size_t)512 * 64 * 2);
  __bf16* W1Fl = (__bf16*)alloc((size_t)512 * 64 * 2);
  f16* WhB1 = (f16*)alloc((size_t)32 * N * 64 * 2);  // 8 MB
  float* E1 = (float*)alloc((size_t)32 * N * 4);
  float* G1 = (float*)alloc((size_t)32 * N * 4);
  f16* F1 = (f16*)alloc((size_t)32 * N * 2);
  f16* H1 = (f16*)alloc((size_t)32 * N * 2);
  float* x = (float*)alloc((size_t)B * N * 512 * 4);  // 16 MB
  float* pC2 = (float*)alloc((size_t)B * KS2 * N * 64 * 4);  // 8 MB
  f16* WhB2 = (f16*)alloc((size_t)B * N * 64 * 2);
  float* E2 = (float*)alloc((size_t)B * N * 4);
  float* G2 = (float*)alloc((size_t)B * N * 4);
  f16* F2 = (f16*)alloc((size_t)B * N * 2);
  f16* H2 = (f16*)alloc((size_t)B * N * 2);
  float* img = (float*)alloc((size_t)B * N * 64 * 4);  // 2 MB
  float* Wh3 = (float*)alloc((size_t)B * N * 16 * 4);
  float* pAcc2 = (float*)alloc((size_t)B * JS2 * N * 64 * 4);  // 8 MB
  float* pSum2 = (float*)alloc((size_t)B * JS2 * N * 4);

  build_plane_k<<<dim3(N), dim3(256), 0, stream>>>(adj, plane);
  swizw_k<<<dim3(32, 8), dim3(256), 0, stream>>>(Ws, WsFh, WsFl, 128);
  swizw_k<<<dim3(128, 1), dim3(256), 0, stream>>>(W1, W1Fh, W1Fl, 512);

  // layer 1: fused-epilogue GEMM (KS=1) + attention (JS=1)
  gemm_mfma_k<<<dim3(N / 32, 32, 1), dim3(128), 0, stream>>>(
      slices, WsFh, WsFl, As, WhB1, E1, G1, F1, H1, (float*)nullptr,
      128, 1, (long)N * 128);
  attn_k<<<dim3(N / 128, 1, 32), dim3(256), 0, stream>>>(
      WhB1, E1, G1, F1, H1, plane, x, 512, (long)N * 512,
      1, (float*)nullptr, (float*)nullptr);

  // layer 2: K-split GEMM (KS=4) + epilogue + attention (JS=4) + combine
  gemm_mfma_k<<<dim3(N / 32, 4, KS2), dim3(128), 0, stream>>>(
      x, W1Fh, W1Fl, a1, (f16*)nullptr, (float*)nullptr, (float*)nullptr,
      (f16*)nullptr, (f16*)nullptr, pC2, 512, KS2, (long)N * 512);
  gemm_epi_k<<<dim3(N / 16, 4), dim3(256), 0, stream>>>(
      pC2, a1, WhB2, E2, G2, F2, H2, KS2);
  attn_k<<<dim3(N / 128, JS2, 4), dim3(256), 0, stream>>>(
      WhB2, E2, G2, F2, H2, plane, (float*)nullptr, 64, (long)N * 64,
      JS2, pAcc2, pSum2);
  combine_k<<<dim3(B * N * 16 / 256), dim3(256), 0, stream>>>(pAcc2, pSum2, img, out, JS2);

  // layer 3
  gemm16_k<<<dim3(N / 16, B), dim3(256), 0, stream>>>(img, W2, Wh3);
  layer3_k<<<dim3(B), dim3(256), 0, stream>>>(Wh3, a2, plane, out + (size_t)B * N * 64);
}

// Round 7
// 228.314 us; speedup vs baseline: 1.1450x; 1.1450x over previous
//
#include <hip/hip_runtime.h>
#include <hip/hip_bf16.h>
#include <cstdint>

// GAT 3-layer pipeline, MI355X. B=4, N=2048, Fin=128, nhid=64, H=8, emb=64, nclass=16.
// fp32 tensors; d_out = [image_feature (4*2048*64) | pre (4*16)] fp32.
// Round 7: revert attention numerics to r5 (bf16 P-gen, depth-2 ping-pong — proven
// 74.9us), but 16 rows/wave instead of 32: same total P-gen VALU, 2x waves (16/CU)
// for latency hiding, smaller prefetch buffers (~36 VGPR) that actually fit depth-2.
// Keep r6's K-split x4 layer-2 GEMM with a bf16 epilogue kernel.

#define NN 2048

typedef float f32x4 __attribute__((ext_vector_type(4)));
typedef __bf16 bf16x8 __attribute__((ext_vector_type(8)));

__device__ __forceinline__ unsigned pkbf(float a, float b) {
  __hip_bfloat162 t = __float22bfloat162_rn(make_float2(a, b));
  unsigned r;
  __builtin_memcpy(&r, &t, 4);
  return r;
}

// ---------------- adj -> u16 mask plane (0xFFFF / 0) ----------------
__global__ __launch_bounds__(256) void build_plane_k(const int* __restrict__ adj,
                                                     unsigned short* __restrict__ plane) {
  const int i = blockIdx.x;
#pragma unroll
  for (int jt = 0; jt < NN / 256; ++jt) {
    const int j = jt * 256 + threadIdx.x;
    plane[(long)i * NN + j] = adj[(long)i * NN + j] > 0 ? 0xFFFFu : 0u;
  }
}

// ---------------- W (fp32 [K x 64] per instance) -> bf16 hi/lo B-frag planes --------
// frag pos for (k,n): ((k>>5)*4 + (n>>4))*512 + (((k>>3)&3)*16 + (n&15))*8 + (k&7)
__global__ __launch_bounds__(256) void swizw_k(const float* __restrict__ W,
                                               __bf16* __restrict__ hi,
                                               __bf16* __restrict__ lo, int K) {
  const long inst = blockIdx.y;
  const float* w = W + inst * K * 64;
  __bf16* h = hi + inst * K * 64;
  __bf16* l = lo + inst * K * 64;
  for (int idx = blockIdx.x * 256 + threadIdx.x; idx < K * 64; idx += gridDim.x * 256) {
    const int k = idx >> 6, n = idx & 63;
    const float v = w[idx];
    const __bf16 vh = (__bf16)v;
    const __bf16 vl = (__bf16)(v - (float)vh);
    const int pos = ((k >> 5) * 4 + (n >> 4)) * 512 + (((k >> 3) & 3) * 16 + (n & 15)) * 8 + (k & 7);
    h[pos] = vh;
    l[pos] = vl;
  }
}

// ---------------- MFMA GEMM (M rows, N=64). 128 thr, 32 rows/block. ----------------
// KS==1: fused epilogue -> E/G/F/H fp32 + WhB bf16 frags.  KS>1: fp32 partial C to pC.
struct GemmLd {
  float4 a0, a1;
  bf16x8 bh[4], bl[4];
};

__global__ __launch_bounds__(128) void gemm_mfma_k(
    const float* __restrict__ Aall, const __bf16* __restrict__ WFhi,
    const __bf16* __restrict__ WFlo, const float* __restrict__ avecAll,
    __bf16* __restrict__ WhBAll, float* __restrict__ Eo, float* __restrict__ Go,
    float* __restrict__ Fo, float* __restrict__ Ho, float* __restrict__ pC,
    int K, int KS, long aStrideB) {
  const int p = blockIdx.y;
  const int ks = blockIdx.z;
  const float* A = Aall + (long)(p & 3) * aStrideB;
  const long wfOff = (long)(p >> 2) * K * 64;
  const bf16x8* BhF = (const bf16x8*)(WFhi + wfOff);
  const bf16x8* BlF = (const bf16x8*)(WFlo + wfOff);

  const int t = threadIdx.x, lane = t & 63, wave = t >> 6;
  const int quad = lane >> 4, lm = lane & 15;
  const int i0w = blockIdx.x * 32 + wave * 16;
  const float* Arow = A + (long)(i0w + lm) * K;
  const int kBeg = ks * (K / KS), kEnd = kBeg + K / KS;

  f32x4 acc[4];
#pragma unroll
  for (int nt = 0; nt < 4; ++nt) acc[nt] = (f32x4){0.f, 0.f, 0.f, 0.f};

  auto LOAD = [&](GemmLd& L, int k0) {
    L.a0 = *(const float4*)(Arow + k0 + quad * 8);
    L.a1 = *(const float4*)(Arow + k0 + quad * 8 + 4);
    const int bbase = (k0 >> 5) * 256 + lane;
#pragma unroll
    for (int nt = 0; nt < 4; ++nt) {
      L.bh[nt] = BhF[bbase + nt * 64];
      L.bl[nt] = BlF[bbase + nt * 64];
    }
  };
  auto STEP = [&](const GemmLd& L) {
    const float av8[8] = {L.a0.x, L.a0.y, L.a0.z, L.a0.w, L.a1.x, L.a1.y, L.a1.z, L.a1.w};
    bf16x8 ah, al;
#pragma unroll
    for (int j = 0; j < 8; ++j) {
      const __bf16 h = (__bf16)av8[j];
      ah[j] = h;
      al[j] = (__bf16)(av8[j] - (float)h);
    }
#pragma unroll
    for (int nt = 0; nt < 4; ++nt) {
      acc[nt] = __builtin_amdgcn_mfma_f32_16x16x32_bf16(ah, L.bh[nt], acc[nt], 0, 0, 0);
      acc[nt] = __builtin_amdgcn_mfma_f32_16x16x32_bf16(al, L.bh[nt], acc[nt], 0, 0, 0);
      acc[nt] = __builtin_amdgcn_mfma_f32_16x16x32_bf16(ah, L.bl[nt], acc[nt], 0, 0, 0);
    }
  };

  GemmLd La, Lb;
  LOAD(La, kBeg);
  for (int k0 = kBeg; k0 < kEnd; k0 += 64) {
    LOAD(Lb, k0 + 32);
    STEP(La);
    LOAD(La, (k0 + 64 < kEnd) ? k0 + 64 : kBeg);
    STEP(Lb);
  }

  if (KS > 1) {
    float* pc = pC + ((long)(p * KS + ks) * NN) * 64;
#pragma unroll
    for (int reg = 0; reg < 4; ++reg) {
      const int row = i0w + quad * 4 + reg;
#pragma unroll
      for (int nt = 0; nt < 4; ++nt) pc[(long)row * 64 + nt * 16 + lm] = acc[nt][reg];
    }
    return;
  }

  const float* av = avecAll + (long)(p >> 2) * 128;
  __bf16* WhB = WhBAll + (long)p * NN * 64;
  float* E = Eo + (long)p * NN;
  float* G = Go + (long)p * NN;
  float* F = Fo + (long)p * NN;
  float* Hh = Ho + (long)p * NN;

  float alo[4], ahi[4];
#pragma unroll
  for (int nt = 0; nt < 4; ++nt) {
    alo[nt] = av[nt * 16 + lm];
    ahi[nt] = av[64 + nt * 16 + lm];
  }
#pragma unroll
  for (int reg = 0; reg < 4; ++reg) {
    float es = 0.f, ed = 0.f;
#pragma unroll
    for (int nt = 0; nt < 4; ++nt) {
      es += acc[nt][reg] * alo[nt];
      ed += acc[nt][reg] * ahi[nt];
    }
#pragma unroll
    for (int m = 1; m < 16; m <<= 1) {
      es += __shfl_xor(es, m);
      ed += __shfl_xor(ed, m);
    }
    if (lm == 0) {
      const int r = i0w + quad * 4 + reg;
      E[r] = __expf(es);
      G[r] = __expf(0.2f * es);
      F[r] = __expf(ed);
      Hh[r] = __expf(0.2f * ed);
    }
  }

  const int r0 = i0w + quad * 4;
  const long base = ((long)(r0 >> 5) * 4) * 512 + (((r0 >> 3) & 3) * 16 + lm) * 8 + (r0 & 7);
#pragma unroll
  for (int nt = 0; nt < 4; ++nt) {
    const unsigned lo32 = pkbf(acc[nt][0], acc[nt][1]);
    const unsigned hi32 = pkbf(acc[nt][2], acc[nt][3]);
    *(uint2*)(WhB + base + nt * 512) = make_uint2(lo32, hi32);
  }
}

// ---------------- layer-2 GEMM epilogue: sum KS partials -> E/G/F/H + WhB bf16 ----
__global__ __launch_bounds__(256) void gemm_epi_k(
    const float* __restrict__ pC, const float* __restrict__ avec,
    __bf16* __restrict__ WhBAll, float* __restrict__ Eo, float* __restrict__ Go,
    float* __restrict__ Fo, float* __restrict__ Ho, int KS) {
  const int inst = blockIdx.y;
  const int t = threadIdx.x;
  const int row = blockIdx.x * 16 + (t >> 4);
  const int cg = t & 15;
  f32x4 c = (f32x4){0.f, 0.f, 0.f, 0.f};
  for (int ks = 0; ks < KS; ++ks)
    c += *(const f32x4*)(pC + (((long)(inst * KS + ks) * NN) + row) * 64 + cg * 4);
  float es = 0.f, ed = 0.f;
#pragma unroll
  for (int q = 0; q < 4; ++q) {
    const int n = cg * 4 + q;
    es += c[q] * avec[n];
    ed += c[q] * avec[64 + n];
  }
#pragma unroll
  for (int m = 1; m < 16; m <<= 1) {
    es += __shfl_xor(es, m);
    ed += __shfl_xor(ed, m);
  }
  if (cg == 0) {
    Eo[(long)inst * NN + row] = __expf(es);
    Go[(long)inst * NN + row] = __expf(0.2f * es);
    Fo[(long)inst * NN + row] = __expf(ed);
    Ho[(long)inst * NN + row] = __expf(0.2f * ed);
  }
  __bf16* WhB = WhBAll + (long)inst * NN * 64;
#pragma unroll
  for (int q = 0; q < 4; ++q) {
    const int n = cg * 4 + q;
    const int pos = ((row >> 5) * 4 + (n >> 4)) * 512 + (((row >> 3) & 3) * 16 + (n & 15)) * 8 + (row & 7);
    WhB[pos] = (__bf16)c[q];
  }
}

// ---------------- attention: P = mask & max(E*F, G*H), out = elu((P@WhB)/rowsum) ----
// 16 rows per wave (one A-frag group), 4 waves/block (64 rows/block), depth-2
// ping-pong prefetch. Same numerics as round 5; 2x wave count for latency hiding.
struct AttnLd {
  float4 Fa, Fc, Ha, Hc;
  uint4 m0;
  bf16x8 b[4];
};

__global__ __launch_bounds__(256) void attn_k(
    const __bf16* __restrict__ WhBAll, const float* __restrict__ Eb,
    const float* __restrict__ Gb, const float* __restrict__ Fb,
    const float* __restrict__ Hb, const unsigned short* __restrict__ plane,
    float* __restrict__ out1, float* __restrict__ out2, int rowStride, long strideB,
    int jsCount, float* __restrict__ partAcc, float* __restrict__ partSum) {
  const int p = blockIdx.z;
  const int js = blockIdx.y;
  const bf16x8* bp = (const bf16x8*)(WhBAll + (long)p * NN * 64);
  const float* E = Eb + (long)p * NN;
  const float* G = Gb + (long)p * NN;
  const float* F = Fb + (long)p * NN;
  const float* Hv = Hb + (long)p * NN;
  const int t = threadIdx.x, lane = t & 63, wave = t >> 6;
  const int quad = lane >> 4, lm = lane & 15;
  const int i0 = blockIdx.x * 64 + wave * 16;
  const int kbBeg = js * (64 / jsCount);
  const int kbEnd = kbBeg + 64 / jsCount;

  const float E0 = E[i0 + lm], G0 = G[i0 + lm];
  const unsigned short* mp0 = plane + (long)(i0 + lm) * NN;

  bf16x8 ones;
#pragma unroll
  for (int j = 0; j < 8; ++j) ones[j] = (lm == 0) ? (__bf16)1.0f : (__bf16)0.0f;

  f32x4 acc0[4], sum0;
#pragma unroll
  for (int nt = 0; nt < 4; ++nt) acc0[nt] = (f32x4){0.f, 0.f, 0.f, 0.f};
  sum0 = (f32x4){0.f, 0.f, 0.f, 0.f};

  auto LOAD = [&](AttnLd& L, int kb) {
    const int c0 = kb * 32 + quad * 8;
    L.Fa = *(const float4*)(F + c0);
    L.Fc = *(const float4*)(F + c0 + 4);
    L.Ha = *(const float4*)(Hv + c0);
    L.Hc = *(const float4*)(Hv + c0 + 4);
    L.m0 = *(const uint4*)(mp0 + c0);
#pragma unroll
    for (int nt = 0; nt < 4; ++nt) L.b[nt] = bp[(kb * 4 + nt) * 64 + lane];
  };
  auto STEP = [&](const AttnLd& L) {
    const float Fv8[8] = {L.Fa.x, L.Fa.y, L.Fa.z, L.Fa.w, L.Fc.x, L.Fc.y, L.Fc.z, L.Fc.w};
    const float Hv8[8] = {L.Ha.x, L.Ha.y, L.Ha.z, L.Ha.w, L.Hc.x, L.Hc.y, L.Hc.z, L.Hc.w};
    union { uint4 u; bf16x8 v; } A0;
    A0.u.x = pkbf(fmaxf(E0 * Fv8[0], G0 * Hv8[0]), fmaxf(E0 * Fv8[1], G0 * Hv8[1])) & L.m0.x;
    A0.u.y = pkbf(fmaxf(E0 * Fv8[2], G0 * Hv8[2]), fmaxf(E0 * Fv8[3], G0 * Hv8[3])) & L.m0.y;
    A0.u.z = pkbf(fmaxf(E0 * Fv8[4], G0 * Hv8[4]), fmaxf(E0 * Fv8[5], G0 * Hv8[5])) & L.m0.z;
    A0.u.w = pkbf(fmaxf(E0 * Fv8[6], G0 * Hv8[6]), fmaxf(E0 * Fv8[7], G0 * Hv8[7])) & L.m0.w;
#pragma unroll
    for (int nt = 0; nt < 4; ++nt)
      acc0[nt] = __builtin_amdgcn_mfma_f32_16x16x32_bf16(A0.v, L.b[nt], acc0[nt], 0, 0, 0);
    sum0 = __builtin_amdgcn_mfma_f32_16x16x32_bf16(A0.v, ones, sum0, 0, 0, 0);
  };

  AttnLd La, Lb;
  LOAD(La, kbBeg);
  for (int kb = kbBeg; kb < kbEnd; kb += 2) {
    LOAD(Lb, kb + 1);
    STEP(La);
    LOAD(La, (kb + 2 < kbEnd) ? kb + 2 : kbBeg);
    STEP(Lb);
  }

  if (jsCount == 1) {
#pragma unroll
    for (int reg = 0; reg < 4; ++reg) {
      const int row = i0 + quad * 4 + reg;
      const float ls = __shfl(sum0[reg], quad * 16);
      const float il = ls > 0.f ? 1.f / ls : 0.f;
#pragma unroll
      for (int nt = 0; nt < 4; ++nt) {
        float v = acc0[nt][reg] * il;
        v = v > 0.f ? v : expm1f(v);  // elu
        const long o = (long)(p & 3) * strideB + (long)row * rowStride + (p >> 2) * 64 + nt * 16 + lm;
        out1[o] = v;
        if (out2) out2[o] = v;
      }
    }
  } else {
    float* pAcc = partAcc + ((long)p * jsCount + js) * NN * 64;
    float* pSum = partSum + ((long)p * jsCount + js) * NN;
#pragma unroll
    for (int reg = 0; reg < 4; ++reg) {
      const int row = i0 + quad * 4 + reg;
#pragma unroll
      for (int nt = 0; nt < 4; ++nt) pAcc[(long)row * 64 + nt * 16 + lm] = acc0[nt][reg];
      if (lm == 0) pSum[row] = sum0[reg];
    }
  }
}

// ---------------- combine j-split partials: normalize + elu + dual write ----------------
__global__ __launch_bounds__(256) void combine_k(const float* __restrict__ partAcc,
                                                 const float* __restrict__ partSum,
                                                 float* __restrict__ img,
                                                 float* __restrict__ out, int JS) {
  const long idx = (long)blockIdx.x * 256 + threadIdx.x;
  const int cg = idx & 15;
  const int row = (int)((idx >> 4) & (NN - 1));
  const int inst = (int)(idx >> 15);
  f32x4 v = (f32x4){0.f, 0.f, 0.f, 0.f};
  float s = 0.f;
  for (int js = 0; js < JS; ++js) {
    const long b = ((long)inst * JS + js) * NN;
    v += *(const f32x4*)(partAcc + (b + row) * 64 + cg * 4);
    s += partSum[b + row];
  }
  const float il = s > 0.f ? 1.f / s : 0.f;
  f32x4 r;
#pragma unroll
  for (int q = 0; q < 4; ++q) {
    float x = v[q] * il;
    r[q] = x > 0.f ? x : expm1f(x);
  }
  const long o = ((long)inst * NN + row) * 64 + cg * 4;
  *(f32x4*)(img + o) = r;
  *(f32x4*)(out + o) = r;
}

// ---------------- layer-3 Wh3 = imgfeat @ W2 (K=64, Nc=16), fp32 ----------------
__global__ __launch_bounds__(256) void gemm16_k(const float* __restrict__ Aall,
                                                const float* __restrict__ Bw,
                                                float* __restrict__ Call) {
  const int bb = blockIdx.y;
  const float* A = Aall + (long)bb * NN * 64;
  float* C = Call + (long)bb * NN * 16;
  const int r0 = blockIdx.x * 16;
  const int t = threadIdx.x;
  __shared__ float As[16][65];
  __shared__ float Bs[64][16];
  const int c = t & 15, r = t >> 4;
#pragma unroll
  for (int q = 0; q < 4; ++q) {
    const int idx = q * 256 + t;
    As[idx >> 6][idx & 63] = A[(long)(r0 + (idx >> 6)) * 64 + (idx & 63)];
    Bs[idx >> 4][idx & 15] = Bw[idx];
  }
  __syncthreads();
  float acc = 0.f;
#pragma unroll 16
  for (int k = 0; k < 64; ++k) acc += As[r][k] * Bs[k][c];
  C[(long)(r0 + r) * 16 + c] = acc;
}

// ---------------- layer-3 finalize: only attention row 0 matters ----------------
__global__ __launch_bounds__(256) void layer3_k(const float* __restrict__ Wh3,
                                                const float* __restrict__ a2,
                                                const unsigned short* __restrict__ plane,
                                                float* __restrict__ outPre) {
  const int bb = blockIdx.x, t = threadIdx.x;
  const float* W = Wh3 + (long)bb * NN * 16;
  __shared__ float wsum[4];
  __shared__ float vacc[4][16];
  float alo[16], ahi[16];
#pragma unroll
  for (int c = 0; c < 16; ++c) {
    alo[c] = a2[c];
    ahi[c] = a2[16 + c];
  }
  float es = 0.f;
#pragma unroll
  for (int c = 0; c < 16; ++c) es += W[c] * alo[c];

  float lsum = 0.f;
  float acc[16];
#pragma unroll
  for (int c = 0; c < 16; ++c) acc[c] = 0.f;
  for (int j = t; j < NN; j += 256) {
    float ed = 0.f;
#pragma unroll
    for (int c = 0; c < 16; ++c) ed += W[(long)j * 16 + c] * ahi[c];
    float e = es + ed;
    e = fmaxf(e, 0.2f * e);
    const float pv = plane[j] ? __expf(e) : 0.f;
    lsum += pv;
#pragma unroll
    for (int c = 0; c < 16; ++c) acc[c] += pv * W[(long)j * 16 + c];
  }
#pragma unroll
  for (int off = 32; off > 0; off >>= 1) {
    lsum += __shfl_down(lsum, off);
#pragma unroll
    for (int c = 0; c < 16; ++c) acc[c] += __shfl_down(acc[c], off);
  }
  if ((t & 63) == 0) {
    wsum[t >> 6] = lsum;
#pragma unroll
    for (int c = 0; c < 16; ++c) vacc[t >> 6][c] = acc[c];
  }
  __syncthreads();
  if (t < 16) {
    const float a = vacc[0][t] + vacc[1][t] + vacc[2][t] + vacc[3][t];
    const float l = wsum[0] + wsum[1] + wsum[2] + wsum[3];
    float v = a / l;
    v = v > 0.f ? v : expm1f(v);
    outPre[bb * 16 + t] = v;
  }
}

// ---------------- host ----------------
extern "C" void kernel_launch(void* const* d_in, const int* in_sizes, int n_in,
                              void* d_out, int out_size, void* d_ws, size_t ws_size,
                              hipStream_t stream) {
  (void)in_sizes; (void)n_in; (void)out_size; (void)ws_size;
  constexpr int B = 4, N = NN, JS2 = 4, KS2 = 4;

  const float* slices = (const float*)d_in[0];
  const int* adj = (const int*)d_in[1];
  const float* Ws = (const float*)d_in[2];
  const float* As = (const float*)d_in[3];
  const float* W1 = (const float*)d_in[4];
  const float* a1 = (const float*)d_in[5];
  const float* W2 = (const float*)d_in[6];
  const float* a2 = (const float*)d_in[7];
  float* out = (float*)d_out;

  char* w = (char*)d_ws;
  size_t off = 0;
  auto alloc = [&](size_t bytes) {
    void* ptr = w + off;
    off += (bytes + 255) & ~(size_t)255;
    return ptr;
  };
  unsigned short* plane = (unsigned short*)alloc((size_t)N * N * 2);  // 8 MB
  __bf16* WsFh = (__bf16*)alloc((size_t)8 * 128 * 64 * 2);
  __bf16* WsFl = (__bf16*)alloc((size_t)8 * 128 * 64 * 2);
  __bf16* W1Fh = (__bf16*)alloc((size_t)512 * 64 * 2);
  __bf16* W1Fl = (__bf16*)alloc((size_t)512 * 64 * 2);
  __bf16* WhB1 = (__bf16*)alloc((size_t)32 * N * 64 * 2);  // 8 MB
  float* E1 = (float*)alloc((size_t)32 * N * 4);
  float* G1 = (float*)alloc((size_t)32 * N * 4);
  float* F1 = (float*)alloc((size_t)32 * N * 4);
  float* H1 = (float*)alloc((size_t)32 * N * 4);
  float* x = (float*)alloc((size_t)B * N * 512 * 4);  // 16 MB
  float* pC2 = (float*)alloc((size_t)B * KS2 * N * 64 * 4);  // 8 MB
  __bf16* WhB2 = (__bf16*)alloc((size_t)B * N * 64 * 2);
  float* E2 = (float*)alloc((size_t)B * N * 4);
  float* G2 = (float*)alloc((size_t)B * N * 4);
  float* F2 = (float*)alloc((size_t)B * N * 4);
  float* H2 = (float*)alloc((size_t)B * N * 4);
  float* img = (float*)alloc((size_t)B * N * 64 * 4);  // 2 MB
  float* Wh3 = (float*)alloc((size_t)B * N * 16 * 4);
  float* pAcc2 = (float*)alloc((size_t)B * JS2 * N * 64 * 4);  // 8 MB
  float* pSum2 = (float*)alloc((size_t)B * JS2 * N * 4);

  build_plane_k<<<dim3(N), dim3(256), 0, stream>>>(adj, plane);
  swizw_k<<<dim3(32, 8), dim3(256), 0, stream>>>(Ws, WsFh, WsFl, 128);
  swizw_k<<<dim3(128, 1), dim3(256), 0, stream>>>(W1, W1Fh, W1Fl, 512);

  // layer 1: fused-epilogue GEMM (KS=1) + attention (JS=1, 16 rows/wave)
  gemm_mfma_k<<<dim3(N / 32, 32, 1), dim3(128), 0, stream>>>(
      slices, WsFh, WsFl, As, WhB1, E1, G1, F1, H1, (float*)nullptr,
      128, 1, (long)N * 128);
  attn_k<<<dim3(N / 64, 1, 32), dim3(256), 0, stream>>>(
      WhB1, E1, G1, F1, H1, plane, x, (float*)nullptr, 512, (long)N * 512,
      1, (float*)nullptr, (float*)nullptr);

  // layer 2: K-split GEMM (KS=4) + epilogue + attention (JS=4) + combine
  gemm_mfma_k<<<dim3(N / 32, 4, KS2), dim3(128), 0, stream>>>(
      x, W1Fh, W1Fl, a1, (__bf16*)nullptr, (float*)nullptr, (float*)nullptr,
      (float*)nullptr, (float*)nullptr, pC2, 512, KS2, (long)N * 512);
  gemm_epi_k<<<dim3(N / 16, 4), dim3(256), 0, stream>>>(
      pC2, a1, WhB2, E2, G2, F2, H2, KS2);
  attn_k<<<dim3(N / 64, JS2, 4), dim3(256), 0, stream>>>(
      WhB2, E2, G2, F2, H2, plane, (float*)nullptr, (float*)nullptr, 64, (long)N * 64,
      JS2, pAcc2, pSum2);
  combine_k<<<dim3(B * N * 16 / 256), dim3(256), 0, stream>>>(pAcc2, pSum2, img, out, JS2);

  // layer 3
  gemm16_k<<<dim3(N / 16, B), dim3(256), 0, stream>>>(img, W2, Wh3);
  layer3_k<<<dim3(B), dim3(256), 0, stream>>>(Wh3, a2, plane, out + (size_t)B * N * 64);
}

// Round 8
// 201.335 us; speedup vs baseline: 1.2984x; 1.1340x over previous
//
#include <hip/hip_runtime.h>
#include <hip/hip_bf16.h>
#include <cstdint>

// GAT 3-layer pipeline, MI355X. B=4, N=2048, Fin=128, nhid=64, H=8, emb=64, nclass=16.
// fp32 tensors; d_out = [image_feature (4*2048*64) | pre (4*16)] fp32.
// Round 8: attention = r5's proven 32-rows/wave bf16 structure, but 512-thread blocks
// with an INTERNAL kb-split: waves 0-3 do kb-half 0, waves 4-7 the same rows kb-half 1,
// merged once via LDS. 2x waves (4/SIMD) at IDENTICAL L2 traffic (r7 showed traffic
// doubling kills the TLP gain; kb-partitioning keeps B reads constant).

#define NN 2048

typedef float f32x4 __attribute__((ext_vector_type(4)));
typedef __bf16 bf16x8 __attribute__((ext_vector_type(8)));

__device__ __forceinline__ unsigned pkbf(float a, float b) {
  __hip_bfloat162 t = __float22bfloat162_rn(make_float2(a, b));
  unsigned r;
  __builtin_memcpy(&r, &t, 4);
  return r;
}

// ---------------- adj -> u16 mask plane (0xFFFF / 0) ----------------
__global__ __launch_bounds__(256) void build_plane_k(const int* __restrict__ adj,
                                                     unsigned short* __restrict__ plane) {
  const int i = blockIdx.x;
#pragma unroll
  for (int jt = 0; jt < NN / 256; ++jt) {
    const int j = jt * 256 + threadIdx.x;
    plane[(long)i * NN + j] = adj[(long)i * NN + j] > 0 ? 0xFFFFu : 0u;
  }
}

// ---------------- W (fp32 [K x 64] per instance) -> bf16 hi/lo B-frag planes --------
__global__ __launch_bounds__(256) void swizw_k(const float* __restrict__ W,
                                               __bf16* __restrict__ hi,
                                               __bf16* __restrict__ lo, int K) {
  const long inst = blockIdx.y;
  const float* w = W + inst * K * 64;
  __bf16* h = hi + inst * K * 64;
  __bf16* l = lo + inst * K * 64;
  for (int idx = blockIdx.x * 256 + threadIdx.x; idx < K * 64; idx += gridDim.x * 256) {
    const int k = idx >> 6, n = idx & 63;
    const float v = w[idx];
    const __bf16 vh = (__bf16)v;
    const __bf16 vl = (__bf16)(v - (float)vh);
    const int pos = ((k >> 5) * 4 + (n >> 4)) * 512 + (((k >> 3) & 3) * 16 + (n & 15)) * 8 + (k & 7);
    h[pos] = vh;
    l[pos] = vl;
  }
}

// ---------------- MFMA GEMM (M rows, N=64). 128 thr, 32 rows/block. ----------------
struct GemmLd {
  float4 a0, a1;
  bf16x8 bh[4], bl[4];
};

__global__ __launch_bounds__(128) void gemm_mfma_k(
    const float* __restrict__ Aall, const __bf16* __restrict__ WFhi,
    const __bf16* __restrict__ WFlo, const float* __restrict__ avecAll,
    __bf16* __restrict__ WhBAll, float* __restrict__ Eo, float* __restrict__ Go,
    float* __restrict__ Fo, float* __restrict__ Ho, float* __restrict__ pC,
    int K, int KS, long aStrideB) {
  const int p = blockIdx.y;
  const int ks = blockIdx.z;
  const float* A = Aall + (long)(p & 3) * aStrideB;
  const long wfOff = (long)(p >> 2) * K * 64;
  const bf16x8* BhF = (const bf16x8*)(WFhi + wfOff);
  const bf16x8* BlF = (const bf16x8*)(WFlo + wfOff);

  const int t = threadIdx.x, lane = t & 63, wave = t >> 6;
  const int quad = lane >> 4, lm = lane & 15;
  const int i0w = blockIdx.x * 32 + wave * 16;
  const float* Arow = A + (long)(i0w + lm) * K;
  const int kBeg = ks * (K / KS), kEnd = kBeg + K / KS;

  f32x4 acc[4];
#pragma unroll
  for (int nt = 0; nt < 4; ++nt) acc[nt] = (f32x4){0.f, 0.f, 0.f, 0.f};

  auto LOAD = [&](GemmLd& L, int k0) {
    L.a0 = *(const float4*)(Arow + k0 + quad * 8);
    L.a1 = *(const float4*)(Arow + k0 + quad * 8 + 4);
    const int bbase = (k0 >> 5) * 256 + lane;
#pragma unroll
    for (int nt = 0; nt < 4; ++nt) {
      L.bh[nt] = BhF[bbase + nt * 64];
      L.bl[nt] = BlF[bbase + nt * 64];
    }
  };
  auto STEP = [&](const GemmLd& L) {
    const float av8[8] = {L.a0.x, L.a0.y, L.a0.z, L.a0.w, L.a1.x, L.a1.y, L.a1.z, L.a1.w};
    bf16x8 ah, al;
#pragma unroll
    for (int j = 0; j < 8; ++j) {
      const __bf16 h = (__bf16)av8[j];
      ah[j] = h;
      al[j] = (__bf16)(av8[j] - (float)h);
    }
#pragma unroll
    for (int nt = 0; nt < 4; ++nt) {
      acc[nt] = __builtin_amdgcn_mfma_f32_16x16x32_bf16(ah, L.bh[nt], acc[nt], 0, 0, 0);
      acc[nt] = __builtin_amdgcn_mfma_f32_16x16x32_bf16(al, L.bh[nt], acc[nt], 0, 0, 0);
      acc[nt] = __builtin_amdgcn_mfma_f32_16x16x32_bf16(ah, L.bl[nt], acc[nt], 0, 0, 0);
    }
  };

  GemmLd La, Lb;
  LOAD(La, kBeg);
  for (int k0 = kBeg; k0 < kEnd; k0 += 64) {
    LOAD(Lb, k0 + 32);
    STEP(La);
    LOAD(La, (k0 + 64 < kEnd) ? k0 + 64 : kBeg);
    STEP(Lb);
  }

  if (KS > 1) {
    float* pc = pC + ((long)(p * KS + ks) * NN) * 64;
#pragma unroll
    for (int reg = 0; reg < 4; ++reg) {
      const int row = i0w + quad * 4 + reg;
#pragma unroll
      for (int nt = 0; nt < 4; ++nt) pc[(long)row * 64 + nt * 16 + lm] = acc[nt][reg];
    }
    return;
  }

  const float* av = avecAll + (long)(p >> 2) * 128;
  __bf16* WhB = WhBAll + (long)p * NN * 64;
  float* E = Eo + (long)p * NN;
  float* G = Go + (long)p * NN;
  float* F = Fo + (long)p * NN;
  float* Hh = Ho + (long)p * NN;

  float alo[4], ahi[4];
#pragma unroll
  for (int nt = 0; nt < 4; ++nt) {
    alo[nt] = av[nt * 16 + lm];
    ahi[nt] = av[64 + nt * 16 + lm];
  }
#pragma unroll
  for (int reg = 0; reg < 4; ++reg) {
    float es = 0.f, ed = 0.f;
#pragma unroll
    for (int nt = 0; nt < 4; ++nt) {
      es += acc[nt][reg] * alo[nt];
      ed += acc[nt][reg] * ahi[nt];
    }
#pragma unroll
    for (int m = 1; m < 16; m <<= 1) {
      es += __shfl_xor(es, m);
      ed += __shfl_xor(ed, m);
    }
    if (lm == 0) {
      const int r = i0w + quad * 4 + reg;
      E[r] = __expf(es);
      G[r] = __expf(0.2f * es);
      F[r] = __expf(ed);
      Hh[r] = __expf(0.2f * ed);
    }
  }

  const int r0 = i0w + quad * 4;
  const long base = ((long)(r0 >> 5) * 4) * 512 + (((r0 >> 3) & 3) * 16 + lm) * 8 + (r0 & 7);
#pragma unroll
  for (int nt = 0; nt < 4; ++nt) {
    const unsigned lo32 = pkbf(acc[nt][0], acc[nt][1]);
    const unsigned hi32 = pkbf(acc[nt][2], acc[nt][3]);
    *(uint2*)(WhB + base + nt * 512) = make_uint2(lo32, hi32);
  }
}

// ---------------- layer-2 GEMM epilogue: sum KS partials -> E/G/F/H + WhB bf16 ----
__global__ __launch_bounds__(256) void gemm_epi_k(
    const float* __restrict__ pC, const float* __restrict__ avec,
    __bf16* __restrict__ WhBAll, float* __restrict__ Eo, float* __restrict__ Go,
    float* __restrict__ Fo, float* __restrict__ Ho, int KS) {
  const int inst = blockIdx.y;
  const int t = threadIdx.x;
  const int row = blockIdx.x * 16 + (t >> 4);
  const int cg = t & 15;
  f32x4 c = (f32x4){0.f, 0.f, 0.f, 0.f};
  for (int ks = 0; ks < KS; ++ks)
    c += *(const f32x4*)(pC + (((long)(inst * KS + ks) * NN) + row) * 64 + cg * 4);
  float es = 0.f, ed = 0.f;
#pragma unroll
  for (int q = 0; q < 4; ++q) {
    const int n = cg * 4 + q;
    es += c[q] * avec[n];
    ed += c[q] * avec[64 + n];
  }
#pragma unroll
  for (int m = 1; m < 16; m <<= 1) {
    es += __shfl_xor(es, m);
    ed += __shfl_xor(ed, m);
  }
  if (cg == 0) {
    Eo[(long)inst * NN + row] = __expf(es);
    Go[(long)inst * NN + row] = __expf(0.2f * es);
    Fo[(long)inst * NN + row] = __expf(ed);
    Ho[(long)inst * NN + row] = __expf(0.2f * ed);
  }
  __bf16* WhB = WhBAll + (long)inst * NN * 64;
#pragma unroll
  for (int q = 0; q < 4; ++q) {
    const int n = cg * 4 + q;
    const int pos = ((row >> 5) * 4 + (n >> 4)) * 512 + (((row >> 3) & 3) * 16 + (n & 15)) * 8 + (row & 7);
    WhB[pos] = (__bf16)c[q];
  }
}

// ---------------- attention: P = mask & max(E*F, G*H), out = elu((P@WhB)/rowsum) ----
// 512 threads = 8 waves. Waves 0-3: 128 rows x kb-half 0; waves 4-7: same rows, half 1.
// One LDS combine + barrier at the end. 32 rows/wave, depth-2 ping-pong (r5 numerics).
struct AttnLd {
  float4 Fa, Fc, Ha, Hc;
  uint4 m0, m1;
  bf16x8 b[4];
};

__global__ __launch_bounds__(512) void attn_k(
    const __bf16* __restrict__ WhBAll, const float* __restrict__ Eb,
    const float* __restrict__ Gb, const float* __restrict__ Fb,
    const float* __restrict__ Hb, const unsigned short* __restrict__ plane,
    float* __restrict__ out1, float* __restrict__ out2, int rowStride, long strideB,
    int jsCount, float* __restrict__ partAcc, float* __restrict__ partSum) {
  const int p = blockIdx.z;
  const int js = blockIdx.y;
  const bf16x8* bp = (const bf16x8*)(WhBAll + (long)p * NN * 64);
  const float* E = Eb + (long)p * NN;
  const float* G = Gb + (long)p * NN;
  const float* F = Fb + (long)p * NN;
  const float* Hv = Hb + (long)p * NN;
  const int t = threadIdx.x, lane = t & 63, wave = t >> 6;
  const int rw = wave & 3;      // row-wave (which 32 rows)
  const int half = wave >> 2;   // kb half
  const int quad = lane >> 4, lm = lane & 15;
  const int i0 = blockIdx.x * 128 + rw * 32;
  const int span = 64 / jsCount;          // kb per global js job
  const int kbBeg = js * span + half * (span / 2);
  const int kbEnd = kbBeg + span / 2;

  const float E0 = E[i0 + lm], G0 = G[i0 + lm];
  const float E1 = E[i0 + 16 + lm], G1 = G[i0 + 16 + lm];
  const unsigned short* mp0 = plane + (long)(i0 + lm) * NN;
  const unsigned short* mp1 = plane + (long)(i0 + 16 + lm) * NN;

  bf16x8 ones;
#pragma unroll
  for (int j = 0; j < 8; ++j) ones[j] = (lm == 0) ? (__bf16)1.0f : (__bf16)0.0f;

  f32x4 acc0[4], acc1[4], sum0, sum1;
#pragma unroll
  for (int nt = 0; nt < 4; ++nt) {
    acc0[nt] = (f32x4){0.f, 0.f, 0.f, 0.f};
    acc1[nt] = (f32x4){0.f, 0.f, 0.f, 0.f};
  }
  sum0 = (f32x4){0.f, 0.f, 0.f, 0.f};
  sum1 = (f32x4){0.f, 0.f, 0.f, 0.f};

  auto LOAD = [&](AttnLd& L, int kb) {
    const int c0 = kb * 32 + quad * 8;
    L.Fa = *(const float4*)(F + c0);
    L.Fc = *(const float4*)(F + c0 + 4);
    L.Ha = *(const float4*)(Hv + c0);
    L.Hc = *(const float4*)(Hv + c0 + 4);
    L.m0 = *(const uint4*)(mp0 + c0);
    L.m1 = *(const uint4*)(mp1 + c0);
#pragma unroll
    for (int nt = 0; nt < 4; ++nt) L.b[nt] = bp[(kb * 4 + nt) * 64 + lane];
  };
  auto STEP = [&](const AttnLd& L) {
    const float Fv8[8] = {L.Fa.x, L.Fa.y, L.Fa.z, L.Fa.w, L.Fc.x, L.Fc.y, L.Fc.z, L.Fc.w};
    const float Hv8[8] = {L.Ha.x, L.Ha.y, L.Ha.z, L.Ha.w, L.Hc.x, L.Hc.y, L.Hc.z, L.Hc.w};
    union { uint4 u; bf16x8 v; } A0, A1;
    A0.u.x = pkbf(fmaxf(E0 * Fv8[0], G0 * Hv8[0]), fmaxf(E0 * Fv8[1], G0 * Hv8[1])) & L.m0.x;
    A0.u.y = pkbf(fmaxf(E0 * Fv8[2], G0 * Hv8[2]), fmaxf(E0 * Fv8[3], G0 * Hv8[3])) & L.m0.y;
    A0.u.z = pkbf(fmaxf(E0 * Fv8[4], G0 * Hv8[4]), fmaxf(E0 * Fv8[5], G0 * Hv8[5])) & L.m0.z;
    A0.u.w = pkbf(fmaxf(E0 * Fv8[6], G0 * Hv8[6]), fmaxf(E0 * Fv8[7], G0 * Hv8[7])) & L.m0.w;
    A1.u.x = pkbf(fmaxf(E1 * Fv8[0], G1 * Hv8[0]), fmaxf(E1 * Fv8[1], G1 * Hv8[1])) & L.m1.x;
    A1.u.y = pkbf(fmaxf(E1 * Fv8[2], G1 * Hv8[2]), fmaxf(E1 * Fv8[3], G1 * Hv8[3])) & L.m1.y;
    A1.u.z = pkbf(fmaxf(E1 * Fv8[4], G1 * Hv8[4]), fmaxf(E1 * Fv8[5], G1 * Hv8[5])) & L.m1.z;
    A1.u.w = pkbf(fmaxf(E1 * Fv8[6], G1 * Hv8[6]), fmaxf(E1 * Fv8[7], G1 * Hv8[7])) & L.m1.w;
#pragma unroll
    for (int nt = 0; nt < 4; ++nt) {
      acc0[nt] = __builtin_amdgcn_mfma_f32_16x16x32_bf16(A0.v, L.b[nt], acc0[nt], 0, 0, 0);
      acc1[nt] = __builtin_amdgcn_mfma_f32_16x16x32_bf16(A1.v, L.b[nt], acc1[nt], 0, 0, 0);
    }
    sum0 = __builtin_amdgcn_mfma_f32_16x16x32_bf16(A0.v, ones, sum0, 0, 0, 0);
    sum1 = __builtin_amdgcn_mfma_f32_16x16x32_bf16(A1.v, ones, sum1, 0, 0, 0);
  };

  AttnLd La, Lb;
  LOAD(La, kbBeg);
  for (int kb = kbBeg; kb < kbEnd; kb += 2) {
    LOAD(Lb, kb + 1);
    STEP(La);
    LOAD(La, (kb + 2 < kbEnd) ? kb + 2 : kbBeg);
    STEP(Lb);
  }

  // ---- combine the two kb-halves via LDS (40 floats/lane from waves 4-7) ----
  __shared__ float cmb[4 * 64 * 40];  // 40 KB
  if (half == 1) {
    float* dst = &cmb[(rw * 64 + lane) * 40];
#pragma unroll
    for (int nt = 0; nt < 4; ++nt) {
      *(f32x4*)(dst + nt * 4) = acc0[nt];
      *(f32x4*)(dst + 16 + nt * 4) = acc1[nt];
    }
    *(f32x4*)(dst + 32) = sum0;
    *(f32x4*)(dst + 36) = sum1;
  }
  __syncthreads();
  if (half == 1) return;
  {
    const float* src = &cmb[(rw * 64 + lane) * 40];
#pragma unroll
    for (int nt = 0; nt < 4; ++nt) {
      acc0[nt] += *(const f32x4*)(src + nt * 4);
      acc1[nt] += *(const f32x4*)(src + 16 + nt * 4);
    }
    sum0 += *(const f32x4*)(src + 32);
    sum1 += *(const f32x4*)(src + 36);
  }

  if (jsCount == 1) {
#pragma unroll
    for (int g = 0; g < 2; ++g) {
      const f32x4* acc = g ? acc1 : acc0;
      const f32x4 sm = g ? sum1 : sum0;
#pragma unroll
      for (int reg = 0; reg < 4; ++reg) {
        const int row = i0 + g * 16 + quad * 4 + reg;
        const float ls = __shfl(sm[reg], quad * 16);
        const float il = ls > 0.f ? 1.f / ls : 0.f;
#pragma unroll
        for (int nt = 0; nt < 4; ++nt) {
          float v = acc[nt][reg] * il;
          v = v > 0.f ? v : expm1f(v);  // elu
          const long o = (long)(p & 3) * strideB + (long)row * rowStride + (p >> 2) * 64 + nt * 16 + lm;
          out1[o] = v;
          if (out2) out2[o] = v;
        }
      }
    }
  } else {
    float* pAcc = partAcc + ((long)p * jsCount + js) * NN * 64;
    float* pSum = partSum + ((long)p * jsCount + js) * NN;
#pragma unroll
    for (int g = 0; g < 2; ++g) {
      const f32x4* acc = g ? acc1 : acc0;
      const f32x4 sm = g ? sum1 : sum0;
#pragma unroll
      for (int reg = 0; reg < 4; ++reg) {
        const int row = i0 + g * 16 + quad * 4 + reg;
#pragma unroll
        for (int nt = 0; nt < 4; ++nt) pAcc[(long)row * 64 + nt * 16 + lm] = acc[nt][reg];
        if (lm == 0) pSum[row] = sm[reg];
      }
    }
  }
}

// ---------------- combine j-split partials: normalize + elu + dual write ----------------
__global__ __launch_bounds__(256) void combine_k(const float* __restrict__ partAcc,
                                                 const float* __restrict__ partSum,
                                                 float* __restrict__ img,
                                                 float* __restrict__ out, int JS) {
  const long idx = (long)blockIdx.x * 256 + threadIdx.x;
  const int cg = idx & 15;
  const int row = (int)((idx >> 4) & (NN - 1));
  const int inst = (int)(idx >> 15);
  f32x4 v = (f32x4){0.f, 0.f, 0.f, 0.f};
  float s = 0.f;
  for (int js = 0; js < JS; ++js) {
    const long b = ((long)inst * JS + js) * NN;
    v += *(const f32x4*)(partAcc + (b + row) * 64 + cg * 4);
    s += partSum[b + row];
  }
  const float il = s > 0.f ? 1.f / s : 0.f;
  f32x4 r;
#pragma unroll
  for (int q = 0; q < 4; ++q) {
    float x = v[q] * il;
    r[q] = x > 0.f ? x : expm1f(x);
  }
  const long o = ((long)inst * NN + row) * 64 + cg * 4;
  *(f32x4*)(img + o) = r;
  *(f32x4*)(out + o) = r;
}

// ---------------- layer-3 Wh3 = imgfeat @ W2 (K=64, Nc=16), fp32 ----------------
__global__ __launch_bounds__(256) void gemm16_k(const float* __restrict__ Aall,
                                                const float* __restrict__ Bw,
                                                float* __restrict__ Call) {
  const int bb = blockIdx.y;
  const float* A = Aall + (long)bb * NN * 64;
  float* C = Call + (long)bb * NN * 16;
  const int r0 = blockIdx.x * 16;
  const int t = threadIdx.x;
  __shared__ float As[16][65];
  __shared__ float Bs[64][16];
  const int c = t & 15, r = t >> 4;
#pragma unroll
  for (int q = 0; q < 4; ++q) {
    const int idx = q * 256 + t;
    As[idx >> 6][idx & 63] = A[(long)(r0 + (idx >> 6)) * 64 + (idx & 63)];
    Bs[idx >> 4][idx & 15] = Bw[idx];
  }
  __syncthreads();
  float acc = 0.f;
#pragma unroll 16
  for (int k = 0; k < 64; ++k) acc += As[r][k] * Bs[k][c];
  C[(long)(r0 + r) * 16 + c] = acc;
}

// ---------------- layer-3 finalize: only attention row 0 matters ----------------
__global__ __launch_bounds__(256) void layer3_k(const float* __restrict__ Wh3,
                                                const float* __restrict__ a2,
                                                const unsigned short* __restrict__ plane,
                                                float* __restrict__ outPre) {
  const int bb = blockIdx.x, t = threadIdx.x;
  const float* W = Wh3 + (long)bb * NN * 16;
  __shared__ float wsum[4];
  __shared__ float vacc[4][16];
  float alo[16], ahi[16];
#pragma unroll
  for (int c = 0; c < 16; ++c) {
    alo[c] = a2[c];
    ahi[c] = a2[16 + c];
  }
  float es = 0.f;
#pragma unroll
  for (int c = 0; c < 16; ++c) es += W[c] * alo[c];

  float lsum = 0.f;
  float acc[16];
#pragma unroll
  for (int c = 0; c < 16; ++c) acc[c] = 0.f;
  for (int j = t; j < NN; j += 256) {
    float ed = 0.f;
#pragma unroll
    for (int c = 0; c < 16; ++c) ed += W[(long)j * 16 + c] * ahi[c];
    float e = es + ed;
    e = fmaxf(e, 0.2f * e);
    const float pv = plane[j] ? __expf(e) : 0.f;
    lsum += pv;
#pragma unroll
    for (int c = 0; c < 16; ++c) acc[c] += pv * W[(long)j * 16 + c];
  }
#pragma unroll
  for (int off = 32; off > 0; off >>= 1) {
    lsum += __shfl_down(lsum, off);
#pragma unroll
    for (int c = 0; c < 16; ++c) acc[c] += __shfl_down(acc[c], off);
  }
  if ((t & 63) == 0) {
    wsum[t >> 6] = lsum;
#pragma unroll
    for (int c = 0; c < 16; ++c) vacc[t >> 6][c] = acc[c];
  }
  __syncthreads();
  if (t < 16) {
    const float a = vacc[0][t] + vacc[1][t] + vacc[2][t] + vacc[3][t];
    const float l = wsum[0] + wsum[1] + wsum[2] + wsum[3];
    float v = a / l;
    v = v > 0.f ? v : expm1f(v);
    outPre[bb * 16 + t] = v;
  }
}

// ---------------- host ----------------
extern "C" void kernel_launch(void* const* d_in, const int* in_sizes, int n_in,
                              void* d_out, int out_size, void* d_ws, size_t ws_size,
                              hipStream_t stream) {
  (void)in_sizes; (void)n_in; (void)out_size; (void)ws_size;
  constexpr int B = 4, N = NN, JS2 = 4, KS2 = 4;

  const float* slices = (const float*)d_in[0];
  const int* adj = (const int*)d_in[1];
  const float* Ws = (const float*)d_in[2];
  const float* As = (const float*)d_in[3];
  const float* W1 = (const float*)d_in[4];
  const float* a1 = (const float*)d_in[5];
  const float* W2 = (const float*)d_in[6];
  const float* a2 = (const float*)d_in[7];
  float* out = (float*)d_out;

  char* w = (char*)d_ws;
  size_t off = 0;
  auto alloc = [&](size_t bytes) {
    void* ptr = w + off;
    off += (bytes + 255) & ~(size_t)255;
    return ptr;
  };
  unsigned short* plane = (unsigned short*)alloc((size_t)N * N * 2);  // 8 MB
  __bf16* WsFh = (__bf16*)alloc((size_t)8 * 128 * 64 * 2);
  __bf16* WsFl = (__bf16*)alloc((size_t)8 * 128 * 64 * 2);
  __bf16* W1Fh = (__bf16*)alloc((size_t)512 * 64 * 2);
  __bf16* W1Fl = (__bf16*)alloc((size_t)512 * 64 * 2);
  __bf16* WhB1 = (__bf16*)alloc((size_t)32 * N * 64 * 2);  // 8 MB
  float* E1 = (float*)alloc((size_t)32 * N * 4);
  float* G1 = (float*)alloc((size_t)32 * N * 4);
  float* F1 = (float*)alloc((size_t)32 * N * 4);
  float* H1 = (float*)alloc((size_t)32 * N * 4);
  float* x = (float*)alloc((size_t)B * N * 512 * 4);  // 16 MB
  float* pC2 = (float*)alloc((size_t)B * KS2 * N * 64 * 4);  // 8 MB
  __bf16* WhB2 = (__bf16*)alloc((size_t)B * N * 64 * 2);
  float* E2 = (float*)alloc((size_t)B * N * 4);
  float* G2 = (float*)alloc((size_t)B * N * 4);
  float* F2 = (float*)alloc((size_t)B * N * 4);
  float* H2 = (float*)alloc((size_t)B * N * 4);
  float* img = (float*)alloc((size_t)B * N * 64 * 4);  // 2 MB
  float* Wh3 = (float*)alloc((size_t)B * N * 16 * 4);
  float* pAcc2 = (float*)alloc((size_t)B * JS2 * N * 64 * 4);  // 8 MB
  float* pSum2 = (float*)alloc((size_t)B * JS2 * N * 4);

  build_plane_k<<<dim3(N), dim3(256), 0, stream>>>(adj, plane);
  swizw_k<<<dim3(32, 8), dim3(256), 0, stream>>>(Ws, WsFh, WsFl, 128);
  swizw_k<<<dim3(128, 1), dim3(256), 0, stream>>>(W1, W1Fh, W1Fl, 512);

  // layer 1: fused-epilogue GEMM (KS=1) + attention (JS=1, internal kb-split x2)
  gemm_mfma_k<<<dim3(N / 32, 32, 1), dim3(128), 0, stream>>>(
      slices, WsFh, WsFl, As, WhB1, E1, G1, F1, H1, (float*)nullptr,
      128, 1, (long)N * 128);
  attn_k<<<dim3(N / 128, 1, 32), dim3(512), 0, stream>>>(
      WhB1, E1, G1, F1, H1, plane, x, (float*)nullptr, 512, (long)N * 512,
      1, (float*)nullptr, (float*)nullptr);

  // layer 2: K-split GEMM (KS=4) + epilogue + attention (JS=4 x internal 2) + combine
  gemm_mfma_k<<<dim3(N / 32, 4, KS2), dim3(128), 0, stream>>>(
      x, W1Fh, W1Fl, a1, (__bf16*)nullptr, (float*)nullptr, (float*)nullptr,
      (float*)nullptr, (float*)nullptr, pC2, 512, KS2, (long)N * 512);
  gemm_epi_k<<<dim3(N / 16, 4), dim3(256), 0, stream>>>(
      pC2, a1, WhB2, E2, G2, F2, H2, KS2);
  attn_k<<<dim3(N / 128, JS2, 4), dim3(512), 0, stream>>>(
      WhB2, E2, G2, F2, H2, plane, (float*)nullptr, (float*)nullptr, 64, (long)N * 64,
      JS2, pAcc2, pSum2);
  combine_k<<<dim3(B * N * 16 / 256), dim3(256), 0, stream>>>(pAcc2, pSum2, img, out, JS2);

  // layer 3
  gemm16_k<<<dim3(N / 16, B), dim3(256), 0, stream>>>(img, W2, Wh3);
  layer3_k<<<dim3(B), dim3(256), 0, stream>>>(Wh3, a2, plane, out + (size_t)B * N * 64);
}